// Round 13
// baseline (405.491 us; speedup 1.0000x reference)
//
#include <hip/hip_runtime.h>
#include <hip/hip_bf16.h>

#define N_NODES 50000
#define E_EDGES 800000
#define D_MODEL 256
#define H_HEADS 8
#define HDIM    32
#define F_FFN   1024
#define ATT_SCALE 0.0625f   // 256^-0.5
#define LN_EPS  1e-5f
#define NB_SCAN 196         // ceil(N_NODES/256)

typedef __attribute__((ext_vector_type(8))) short bf16x8;
typedef __attribute__((ext_vector_type(8))) unsigned short u16x8;
typedef __attribute__((ext_vector_type(4))) float f32x4;

__device__ __forceinline__ float bf2f(__hip_bfloat16 v) { return __bfloat162float(v); }
__device__ __forceinline__ __hip_bfloat16 f2bf(float v) { return __float2bfloat16(v); }
__device__ __forceinline__ unsigned short bfbits(float f) {
    __hip_bfloat16 h = __float2bfloat16(f);
    return *reinterpret_cast<unsigned short*>(&h);
}

// unpack 8 consecutive bf16 (16B aligned) -> 8 floats
__device__ __forceinline__ void unpack_bf8(uint4 u, float* f) {
    f[0] = __uint_as_float(u.x << 16); f[1] = __uint_as_float(u.x & 0xFFFF0000u);
    f[2] = __uint_as_float(u.y << 16); f[3] = __uint_as_float(u.y & 0xFFFF0000u);
    f[4] = __uint_as_float(u.z << 16); f[5] = __uint_as_float(u.z & 0xFFFF0000u);
    f[6] = __uint_as_float(u.w << 16); f[7] = __uint_as_float(u.w & 0xFFFF0000u);
}

// VALU-only quad reduce: v + dpp_perm(v). CTRL 0xB1 = xor1, 0x4E = xor2 (within quad).
template<int CTRL>
__device__ __forceinline__ float dpp_add(float v) {
    int t = __builtin_amdgcn_update_dpp(0, __float_as_int(v), CTRL, 0xF, 0xF, true);
    return v + __int_as_float(t);
}

// async global->LDS, 16B per lane; LDS dest must be wave-uniform base (+lane*16 implicit)
__device__ __forceinline__ void load_lds16(const void* g, void* l) {
    __builtin_amdgcn_global_load_lds(
        (const __attribute__((address_space(1))) unsigned*)g,
        (__attribute__((address_space(3))) unsigned*)l, 16, 0, 0);
}

#define WAITV(N) asm volatile("s_waitcnt vmcnt(" #N ")" ::: "memory")
#define SBAR()   { __builtin_amdgcn_sched_barrier(0); __builtin_amdgcn_s_barrier(); \
                   __builtin_amdgcn_sched_barrier(0); }

// Column permutation (16x4 transpose within each 64-col block):
//   gemm perm-col p holds logical col T(p) = (p&~63) + ((p&15)<<2) + ((p>>4)&3)
// The packed epilogue stores each lane's 4 nj-values at contiguous logical cols ->
// outputs land in ORIGINAL logical order (att/wt2 consumers unchanged).

// ---------------- prep: edge-count + cvt_x + wtq transpose + bqp + zero scnt ---------
// counts is zeroed by hipMemsetAsync BEFORE this kernel (stream-ordered).
// cursor is zeroed inside scan_blk (touches every node anyway).
#define PREP_E   E_EDGES
#define PREP_X   3200000                    // N*256/4 float4 units
#define PREP_WQ  (768 * 256)
#define PREP_BQ  768
#define PREP_TOT (PREP_E + PREP_X + PREP_WQ + PREP_BQ + 1)
__global__ void prep_kernel(const int* __restrict__ rows, unsigned* __restrict__ counts,
                            const float* __restrict__ x, unsigned short* __restrict__ xb,
                            const float* __restrict__ wq, __hip_bfloat16* __restrict__ wtq,
                            const float* __restrict__ bq, float* __restrict__ bqp,
                            unsigned* __restrict__ scnt) {
    int i = blockIdx.x * blockDim.x + threadIdx.x;
    if (i < PREP_E) {
        atomicAdd(&counts[rows[i]], 1u);
        return;
    }
    i -= PREP_E;
    if (i < PREP_X) {
        float4 v = reinterpret_cast<const float4*>(x)[i];
        ushort4 o;
        o.x = bfbits(v.x); o.y = bfbits(v.y); o.z = bfbits(v.z); o.w = bfbits(v.w);
        reinterpret_cast<ushort4*>(xb)[i] = o;
        return;
    }
    i -= PREP_X;
    if (i < PREP_WQ) {
        int n = i >> 8, k = i & 255;          // n = perm col in [0,768)
        int s = n >> 8, prel = n & 255;       // section 0=q,1=k,2=v
        int d = (prel & 192) + ((prel & 15) << 2) + ((prel >> 4) & 3);  // logical dim
        int co = (d >> 5) * 96 + s * 32 + (d & 31);                     // orig col
        wtq[i] = f2bf(wq[(size_t)k * 768 + co]);
        return;
    }
    i -= PREP_WQ;
    if (i < PREP_BQ) {
        int s = i >> 8, prel = i & 255;
        int d = (prel & 192) + ((prel & 15) << 2) + ((prel >> 4) & 3);
        bqp[i] = bq[(d >> 5) * 96 + s * 32 + (d & 31)];
        return;
    }
    i -= PREP_BQ;
    if (i == 0) *scnt = 0u;
}

// ---------------- single-kernel CSR scan (StreamScan) + cursor zeroing ---------------
__global__ void scan_blk_kernel(const unsigned* __restrict__ counts,
                                unsigned* __restrict__ offs, unsigned* __restrict__ bsum,
                                unsigned* __restrict__ bpre, unsigned* __restrict__ scnt,
                                unsigned* __restrict__ cursor) {
    __shared__ unsigned sh[256];
    __shared__ unsigned lastflag;
    int t = threadIdx.x;
    int i = blockIdx.x * 256 + t;
    unsigned v = (i < N_NODES) ? counts[i] : 0u;
    if (i < N_NODES) cursor[i] = 0u;             // folded memset
    sh[t] = v;
    __syncthreads();
#pragma unroll
    for (int off = 1; off < 256; off <<= 1) {
        unsigned u = (t >= off) ? sh[t - off] : 0u;
        __syncthreads();
        sh[t] += u;
        __syncthreads();
    }
    if (i < N_NODES) offs[i] = sh[t] - v;
    if (t == 255) {
        bsum[blockIdx.x] = sh[255];
        __threadfence();                         // release: bsum visible device-wide
        unsigned ticket = atomicAdd(scnt, 1u);
        lastflag = (ticket == NB_SCAN - 1) ? 1u : 0u;
    }
    __syncthreads();
    if (lastflag) {                              // last block does the 196-entry scan
        __threadfence();                         // acquire side
        unsigned v2 = (t < NB_SCAN) ? atomicAdd(&bsum[t], 0u) : 0u;  // device-scope read
        __syncthreads();
        sh[t] = v2;
        __syncthreads();
#pragma unroll
        for (int off = 1; off < 256; off <<= 1) {
            unsigned u = (t >= off) ? sh[t - off] : 0u;
            __syncthreads();
            sh[t] += u;
            __syncthreads();
        }
        if (t < NB_SCAN) bpre[t] = sh[t] - v2;
        if (t == NB_SCAN - 1) bpre[NB_SCAN] = sh[t];
    }
}

// ---------------- MEGA kernel: roles STRIPED through the grid ------------------------
// Aux blocks interleaved 1:2 with gemm blocks so every dispatch window mixes
// latency-bound scatter with MFMA-bound gemm on each CU.
#define NB_QKV_X 6                       // 768/128
#define NB_QKV_Y ((N_NODES + 127) / 128) // 391
#define NB_QKV   (NB_QKV_X * NB_QKV_Y)   // 2346
#define NB_TRANS 128
#define NB_SCAT2 1024
#define NB_AUXR  (NB_TRANS + 1 + NB_SCAT2)   // 1153
#define NB_MEGA  (NB_QKV + NB_AUXR)          // 3499
__global__ __launch_bounds__(256)
void mega_kernel(const __hip_bfloat16* __restrict__ A,      // xb M x 256
                 const __hip_bfloat16* __restrict__ Wt,     // wtq 768 x 256 (perm)
                 const float* __restrict__ bias,            // bqp
                 __hip_bfloat16* __restrict__ qb,
                 unsigned char* __restrict__ kv8,
                 const int* __restrict__ rows, const int* __restrict__ cols,
                 const unsigned* __restrict__ offsets, const unsigned* __restrict__ bpre,
                 unsigned* __restrict__ cursor, int* __restrict__ scol,
                 const float* __restrict__ w1, __hip_bfloat16* __restrict__ wt1,
                 const float* __restrict__ w2, __hip_bfloat16* __restrict__ wt2,
                 const float* __restrict__ b1, float* __restrict__ b1p,
                 int M) {
    __shared__ short Al[3][128 * 32];
    __shared__ short Bl[3][128 * 32];
    const int bid = blockIdx.x;
    const int t = threadIdx.x;

    const bool is_aux = (bid % 3 == 2) && (bid / 3 < NB_AUXR);
    if (is_aux) {
        const int aid = bid / 3;
        if (aid < NB_TRANS) {
            // ---- 64x64 LDS-tiled transpose role ----
            float* tl = reinterpret_cast<float*>(&Al[0][0]);   // [64][65] f32 = 16.6 KB
            const float* src; __hip_bfloat16* dst;
            int k0, c0, W, KD; bool perm;
            if (aid < 64) {      // w1: 256 k-rows x 1024 cols -> wt1[n*256+k] (perm)
                int kt = aid >> 4, ct = aid & 15;
                k0 = kt * 64; c0 = ct * 64; W = 1024; KD = 256;
                src = w1; dst = wt1; perm = true;
            } else {             // w2: 1024 k-rows x 256 cols -> wt2[n*1024+k]
                int rb2 = aid - 64;
                int kt = rb2 >> 2, ct = rb2 & 3;
                k0 = kt * 64; c0 = ct * 64; W = 256; KD = 1024;
                src = w2; dst = wt2; perm = false;
            }
#pragma unroll
            for (int r = 0; r < 16; ++r) {      // coalesced row loads
                int idx = r * 256 + t;
                int kk = idx >> 6, cc = idx & 63;
                tl[kk * 65 + cc] = src[(size_t)(k0 + kk) * W + c0 + cc];
            }
            __syncthreads();
#pragma unroll
            for (int r = 0; r < 16; ++r) {      // coalesced column stores (along k)
                int idx = r * 256 + t;
                int nl = idx >> 6, kk = idx & 63;
                int cl = perm ? (((nl & 15) << 2) + ((nl >> 4) & 3)) : nl;  // T(nl)
                dst[(size_t)(c0 + nl) * KD + k0 + kk] = f2bf(tl[kk * 65 + cl]);
            }
            return;
        }
        if (aid == NB_TRANS) {
            // ---- b1p role ----
            for (int j = t; j < 1024; j += 256) {
                int f = (j & ~63) + ((j & 15) << 2) + ((j >> 4) & 3);
                b1p[j] = b1[f];
            }
            return;
        }
        // ---- scatter role: grid-stride over edges ----
        int sb = aid - NB_TRANS - 1;            // 0..1023
        for (int e = sb * 256 + t; e < E_EDGES; e += NB_SCAT2 * 256) {
            int r = rows[e];
            unsigned idx = atomicAdd(&cursor[r], 1u);
            scol[offsets[r] + bpre[r >> 8] + idx] = cols[e];
        }
        return;
    }

    // ---- qkv gemm role: dense gemm_id over non-aux bids ----
    int gemm_id = (bid < 3 * NB_AUXR) ? (bid - (bid + 1) / 3) : (bid - NB_AUXR);

    const int wave = t >> 6, lane = t & 63;
    unsigned flat = (unsigned)gemm_id;
    unsigned nwg = NB_QKV;
    unsigned q8 = nwg >> 3, r8 = nwg & 7;
    unsigned xcd = flat & 7, pos = flat >> 3;
    unsigned wg = (xcd < r8) ? (xcd * (q8 + 1) + pos)
                             : (r8 * (q8 + 1) + (xcd - r8) * q8 + pos);
    const int m0 = (int)(wg / NB_QKV_X) * 128;
    const int n0 = (int)(wg % NB_QKV_X) * 128;

    const int wr = wave >> 1, wc = wave & 1;
    const int srow = lane >> 2;
    const int skp  = (lane & 3) ^ ((lane >> 3) & 3);
    const int c0 = wave * 2;
    int ar0 = m0 + c0 * 16 + srow;      if (ar0 >= M) ar0 = M - 1;
    int ar1 = m0 + c0 * 16 + 16 + srow; if (ar1 >= M) ar1 = M - 1;
    const __hip_bfloat16* ga0 = A + (size_t)ar0 * 256 + skp * 8;
    const __hip_bfloat16* ga1 = A + (size_t)ar1 * 256 + skp * 8;
    const __hip_bfloat16* gb0 = Wt + (size_t)(n0 + c0 * 16 + srow) * 256 + skp * 8;
    const __hip_bfloat16* gb1 = Wt + (size_t)(n0 + c0 * 16 + 16 + srow) * 256 + skp * 8;

    const int lh = lane & 15, q = lane >> 4;
    const int qs = q ^ ((lane >> 1) & 3);
    const short* faB = &Al[0][(wr * 64 + lh) * 32 + qs * 8];
    const short* fbB = &Bl[0][(wc * 64 + lh) * 32 + qs * 8];

    f32x4 acc[4][4] = {};

#define GSTAGE(B)                                    \
    load_lds16(ga0, &Al[B][c0 * 512]);               \
    load_lds16(ga1, &Al[B][c0 * 512 + 512]);         \
    load_lds16(gb0, &Bl[B][c0 * 512]);               \
    load_lds16(gb1, &Bl[B][c0 * 512 + 512]);         \
    ga0 += 32; ga1 += 32; gb0 += 32; gb1 += 32;

#define GSTEP(FA, FB)                                                       \
    {                                                                       \
        bf16x8 af[4], bfr[4];                                               \
        _Pragma("unroll")                                                   \
        for (int i = 0; i < 4; i++) {                                       \
            af[i]  = *reinterpret_cast<const bf16x8*>((FA) + i * 16 * 32);  \
            bfr[i] = *reinterpret_cast<const bf16x8*>((FB) + i * 16 * 32);  \
        }                                                                   \
        _Pragma("unroll")                                                   \
        for (int mi = 0; mi < 4; mi++)                                      \
            _Pragma("unroll")                                               \
            for (int nj = 0; nj < 4; nj++)                                  \
                acc[mi][nj] = __builtin_amdgcn_mfma_f32_16x16x32_bf16(      \
                    af[mi], bfr[nj], acc[mi][nj], 0, 0, 0);                 \
    }

    GSTAGE(0)
    GSTAGE(1)
#pragma unroll
    for (int s = 0; s < 8; ++s) {
        if (s < 7) { WAITV(4); } else { WAITV(0); }
        SBAR();
        if (s + 2 < 8) {
            switch ((s + 2) % 3) {
                case 0: { GSTAGE(0) } break;
                case 1: { GSTAGE(1) } break;
                default: { GSTAGE(2) } break;
            }
        }
        const short* fa = faB + (s % 3) * 4096;
        const short* fb = fbB + (s % 3) * 4096;
        GSTEP(fa, fb)
    }
#undef GSTAGE
#undef GSTEP

    const int B = n0 + wc * 64;
    const int gnbase = B + lh;
    float bv[4];
#pragma unroll
    for (int nj = 0; nj < 4; nj++) bv[nj] = bias[gnbase + nj * 16];

    const int sec = B >> 8;                       // 0=q,1=k,2=v (block-uniform)
    const int c = ((B & 255) >> 6) * 16 + lh;     // chunk index [0,64)
#pragma unroll
    for (int mi = 0; mi < 4; mi++) {
        int gmb = m0 + wr * 64 + mi * 16 + q * 4;
#pragma unroll
        for (int r = 0; r < 4; r++) {
            int gm = gmb + r;
            if (gm >= M) continue;
            float v0 = acc[mi][0][r] + bv[0];
            float v1 = acc[mi][1][r] + bv[1];
            float v2 = acc[mi][2][r] + bv[2];
            float v3 = acc[mi][3][r] + bv[3];
            if (sec == 0) {
                ushort4 o;
                o.x = bfbits(v0); o.y = bfbits(v1); o.z = bfbits(v2); o.w = bfbits(v3);
                *reinterpret_cast<ushort4*>(qb + (size_t)gm * 256 + c * 4) = o;
            } else {
                unsigned u = (unsigned)__builtin_amdgcn_cvt_pk_fp8_f32(v0, v1, 0, false);
                u = (unsigned)__builtin_amdgcn_cvt_pk_fp8_f32(v2, v3, (int)u, true);
                *reinterpret_cast<unsigned*>(
                    kv8 + (size_t)gm * 512 + c * 8 + (sec == 1 ? 0 : 4)) = u;
            }
        }
    }
}

// ---------------- ffn1: hbuf = relu(xn @ wt1p^T + b1p), 128x256 tile -----------------
// 512 threads = 8 waves (2x4 of 64x64), K=256, BK=32, 2-phase double-buffered LDS
// (48 KB -> 3 blocks/CU = 24 waves/CU), single __syncthreads per K-step.
// Per wave: 16 MFMA + 8 ds_read_b128 + 3 staging loads per step (2x the MFMA per
// barrier of the old 128x128 4-wave structure). Packed T-perm epilogue.
__global__ __launch_bounds__(512)
void ffn1_kernel(const __hip_bfloat16* __restrict__ A,     // xn M x 256
                 const __hip_bfloat16* __restrict__ Wt,    // wt1 1024 x 256 (perm)
                 const float* __restrict__ bias,           // b1p (perm)
                 __hip_bfloat16* __restrict__ outp,        // hbuf M x 1024
                 int M) {
    __shared__ short LDS[2][(128 + 256) * 32];   // A at [0,4096), B at [4096,12288)
    const int t = threadIdx.x;
    const int wave = t >> 6, lane = t & 63;

    // bijective XCD swizzle over the 2D grid
    unsigned flat = blockIdx.y * gridDim.x + blockIdx.x;
    unsigned nwg = gridDim.x * gridDim.y;
    unsigned q8 = nwg >> 3, r8 = nwg & 7;
    unsigned xcd = flat & 7, pos = flat >> 3;
    unsigned wg = (xcd < r8) ? (xcd * (q8 + 1) + pos)
                             : (r8 * (q8 + 1) + (xcd - r8) * q8 + pos);
    const int m0 = (int)(wg / gridDim.x) * 128;
    const int n0 = (int)(wg % gridDim.x) * 256;

    const int wr = wave >> 2, wc = wave & 3;           // 2x4 of 64x64
    const int srow = lane >> 2;
    const int skp  = (lane & 3) ^ ((lane >> 3) & 3);

    // staging: 24 chunks (A:8, B:16); wave stages {wave, wave+8, wave+16}
    const __hip_bfloat16* gsrc0; int loff0;
    const __hip_bfloat16* gsrc1; int loff1;
    const __hip_bfloat16* gsrc2; int loff2;
    {
#define STAGE_INIT(GS, LO, C)                                                 \
        if ((C) < 8) {                                                        \
            int r_ = m0 + (C) * 16 + srow; if (r_ >= M) r_ = M - 1;           \
            GS = A + (size_t)r_ * 256 + skp * 8;                              \
            LO = (C) * 512;                                                   \
        } else {                                                              \
            GS = Wt + (size_t)(n0 + ((C) - 8) * 16 + srow) * 256 + skp * 8;   \
            LO = 4096 + ((C) - 8) * 512;                                      \
        }
        STAGE_INIT(gsrc0, loff0, wave)
        STAGE_INIT(gsrc1, loff1, wave + 8)
        STAGE_INIT(gsrc2, loff2, wave + 16)
#undef STAGE_INIT
    }

    const int lh = lane & 15, q = lane >> 4;
    const int qs = q ^ ((lane >> 1) & 3);
    const short* fa0 = &LDS[0][(wr * 64 + lh) * 32 + qs * 8];
    const short* fb0 = &LDS[0][4096 + (wc * 64 + lh) * 32 + qs * 8];
    const short* fa1 = &LDS[1][(wr * 64 + lh) * 32 + qs * 8];
    const short* fb1 = &LDS[1][4096 + (wc * 64 + lh) * 32 + qs * 8];

    f32x4 acc[4][4] = {};

#define FFN1_STAGE(BUF)                                      \
    load_lds16(gsrc0, &LDS[BUF][loff0]);                     \
    load_lds16(gsrc1, &LDS[BUF][loff1]);                     \
    load_lds16(gsrc2, &LDS[BUF][loff2]);                     \
    gsrc0 += 32; gsrc1 += 32; gsrc2 += 32;

#define FFN1_STEP(FA, FB)                                                   \
    {                                                                       \
        bf16x8 af[4], bfr[4];                                               \
        _Pragma("unroll")                                                   \
        for (int i = 0; i < 4; i++) {                                       \
            af[i]  = *reinterpret_cast<const bf16x8*>((FA) + i * 16 * 32);  \
            bfr[i] = *reinterpret_cast<const bf16x8*>((FB) + i * 16 * 32);  \
        }                                                                   \
        _Pragma("unroll")                                                   \
        for (int mi = 0; mi < 4; mi++)                                      \
            _Pragma("unroll")                                               \
            for (int nj = 0; nj < 4; nj++)                                  \
                acc[mi][nj] = __builtin_amdgcn_mfma_f32_16x16x32_bf16(      \
                    af[mi], bfr[nj], acc[mi][nj], 0, 0, 0);                 \
    }

    // prologue: stage step 0 into buf0
    FFN1_STAGE(0)
    __syncthreads();

    for (int s = 0; s < 8; s += 2) {
        FFN1_STAGE(1)                      // loads for step s+1
        FFN1_STEP(fa0, fb0)                // compute step s
        __syncthreads();
        if (s < 6) { FFN1_STAGE(0) }       // loads for step s+2
        FFN1_STEP(fa1, fb1)                // compute step s+1
        __syncthreads();
    }
#undef FFN1_STAGE
#undef FFN1_STEP

    // epilogue: relu + bias, packed ushort4 at logical cols (T-perm)
    const int B = n0 + wc * 64;
    const int gnbase = B + lh;
    float bv[4];
#pragma unroll
    for (int nj = 0; nj < 4; nj++) bv[nj] = bias[gnbase + nj * 16];

    const int cb = B + lh * 4;                    // logical col base (T-perm)
#pragma unroll
    for (int mi = 0; mi < 4; mi++) {
        int gmb = m0 + wr * 64 + mi * 16 + q * 4;
#pragma unroll
        for (int r = 0; r < 4; r++) {
            int gm = gmb + r;
            if (gm >= M) continue;
            float v0 = fmaxf(acc[mi][0][r] + bv[0], 0.f);
            float v1 = fmaxf(acc[mi][1][r] + bv[1], 0.f);
            float v2 = fmaxf(acc[mi][2][r] + bv[2], 0.f);
            float v3 = fmaxf(acc[mi][3][r] + bv[3], 0.f);
            ushort4 o;
            o.x = bfbits(v0); o.y = bfbits(v1); o.z = bfbits(v2); o.w = bfbits(v3);
            *reinterpret_cast<ushort4*>(outp + (size_t)gm * F_FFN + cb) = o;
        }
    }
}

// ---------------- ffn2 + fused LN2: out = LN(hbuf @ wt2^T + b2 + xn) ------------------
// 64 x 256 tile, 512 threads = 8 waves (2x4 of 32x64), K=1024, BK=32,
// 2-phase double-buffered LDS (40 KB), single __syncthreads per K-step.
__global__ __launch_bounds__(512)
void ffn2_ln_kernel(const __hip_bfloat16* __restrict__ A,    // M x 1024
                    const __hip_bfloat16* __restrict__ Wt,   // 256 x 1024
                    const float* __restrict__ bias,
                    const __hip_bfloat16* __restrict__ resid,// M x 256
                    const float* __restrict__ g, const float* __restrict__ bb,
                    float* __restrict__ out, int M) {
    __shared__ short LDS[2][(64 + 256) * 32];   // A at [0,2048), B at [2048,10240)
    const int t = threadIdx.x;
    const int wave = t >> 6, lane = t & 63;
    const int m0 = blockIdx.x * 64;
    const int wr = wave >> 2, wc = wave & 3;

    const int srow = lane >> 2;
    const int skp  = (lane & 3) ^ ((lane >> 3) & 3);

    const __hip_bfloat16* gsrc0; int loff0;
    const __hip_bfloat16* gsrc1; int loff1;
    const __hip_bfloat16* gsrc2; int loff2;
    {
#define STAGE_INIT(GS, LO, C)                                            \
        if ((C) < 4) {                                                   \
            int r_ = m0 + (C) * 16 + srow; if (r_ >= M) r_ = M - 1;      \
            GS = A + (size_t)r_ * 1024 + skp * 8;                        \
            LO = (C) * 512;                                              \
        } else {                                                         \
            GS = Wt + (size_t)(((C) - 4) * 16 + srow) * 1024 + skp * 8;  \
            LO = 2048 + ((C) - 4) * 512;                                 \
        }
        STAGE_INIT(gsrc0, loff0, wave)
        STAGE_INIT(gsrc1, loff1, wave + 8)
        int c2 = (wave < 4) ? wave + 16 : 16;
        STAGE_INIT(gsrc2, loff2, c2)
#undef STAGE_INIT
    }

    const int lh = lane & 15, q = lane >> 4;
    const int qs = q ^ ((lane >> 1) & 3);
    const short* fa0 = &LDS[0][(wr * 32 + lh) * 32 + qs * 8];
    const short* fb0 = &LDS[0][2048 + (wc * 64 + lh) * 32 + qs * 8];
    const short* fa1 = &LDS[1][(wr * 32 + lh) * 32 + qs * 8];
    const short* fb1 = &LDS[1][2048 + (wc * 64 + lh) * 32 + qs * 8];

    f32x4 acc[2][4] = {};

#define FFN2_STAGE(BUF)                                      \
    load_lds16(gsrc0, &LDS[BUF][loff0]);                     \
    load_lds16(gsrc1, &LDS[BUF][loff1]);                     \
    if (wave < 4) load_lds16(gsrc2, &LDS[BUF][loff2]);       \
    gsrc0 += 32; gsrc1 += 32; gsrc2 += 32;

#define FFN2_STEP(FA, FB)                                                   \
    {                                                                       \
        bf16x8 af[2], bfr[4];                                               \
        _Pragma("unroll")                                                   \
        for (int i = 0; i < 2; i++)                                         \
            af[i] = *reinterpret_cast<const bf16x8*>((FA) + i * 16 * 32);   \
        _Pragma("unroll")                                                   \
        for (int i = 0; i < 4; i++)                                         \
            bfr[i] = *reinterpret_cast<const bf16x8*>((FB) + i * 16 * 32);  \
        _Pragma("unroll")                                                   \
        for (int mi = 0; mi < 2; mi++)                                      \
            _Pragma("unroll")                                               \
            for (int nj = 0; nj < 4; nj++)                                  \
                acc[mi][nj] = __builtin_amdgcn_mfma_f32_16x16x32_bf16(      \
                    af[mi], bfr[nj], acc[mi][nj], 0, 0, 0);                 \
    }

    FFN2_STAGE(0)
    __syncthreads();

    for (int s = 0; s < 32; s += 2) {
        FFN2_STAGE(1)
        FFN2_STEP(fa0, fb0)
        __syncthreads();
        if (s < 30) { FFN2_STAGE(0) }
        FFN2_STEP(fa1, fb1)
        __syncthreads();
    }
#undef FFN2_STAGE
#undef FFN2_STEP

    const int colbase = wc * 64 + lh;
    float bv[4], gv[4], bbv[4];
#pragma unroll
    for (int nj = 0; nj < 4; nj++) {
        bv[nj]  = bias[colbase + nj * 16];
        gv[nj]  = g[colbase + nj * 16];
        bbv[nj] = bb[colbase + nj * 16];
    }

    float ps[2][4], pq[2][4];
#pragma unroll
    for (int mi = 0; mi < 2; mi++) {
#pragma unroll
        for (int r = 0; r < 4; r++) {
            int gm = m0 + wr * 32 + mi * 16 + q * 4 + r;
            int rgm = (gm < M) ? gm : M - 1;
            float s = 0.f, s2 = 0.f;
#pragma unroll
            for (int nj = 0; nj < 4; nj++) {
                float v = acc[mi][nj][r] + bv[nj]
                        + bf2f(resid[(size_t)rgm * 256 + colbase + nj * 16]);
                acc[mi][nj][r] = v;
                s += v; s2 += v * v;
            }
            ps[mi][r] = s; pq[mi][r] = s2;
        }
    }
#pragma unroll
    for (int off = 1; off <= 8; off <<= 1) {
#pragma unroll
        for (int mi = 0; mi < 2; mi++)
#pragma unroll
            for (int r = 0; r < 4; r++) {
                ps[mi][r] += __shfl_xor(ps[mi][r], off);
                pq[mi][r] += __shfl_xor(pq[mi][r], off);
            }
    }
    float* rs = (float*)(&LDS[0][0]);   // [64][4]
    float* rq = rs + 256;
    if (lh == 0) {
#pragma unroll
        for (int mi = 0; mi < 2; mi++)
#pragma unroll
            for (int r = 0; r < 4; r++) {
                int m = wr * 32 + mi * 16 + q * 4 + r;
                rs[m * 4 + wc] = ps[mi][r];
                rq[m * 4 + wc] = pq[mi][r];
            }
    }
    __syncthreads();

#pragma unroll
    for (int mi = 0; mi < 2; mi++) {
#pragma unroll
        for (int r = 0; r < 4; r++) {
            int m = wr * 32 + mi * 16 + q * 4 + r;
            int gm = m0 + m;
            if (gm >= M) continue;
            float4 rsv = *reinterpret_cast<const float4*>(&rs[m * 4]);
            float4 rqv = *reinterpret_cast<const float4*>(&rq[m * 4]);
            float S  = (rsv.x + rsv.y) + (rsv.z + rsv.w);
            float S2 = (rqv.x + rqv.y) + (rqv.z + rqv.w);
            float mean = S * (1.f / (float)D_MODEL);
            float var  = S2 * (1.f / (float)D_MODEL) - mean * mean;
            float inv  = rsqrtf(var + LN_EPS);
#pragma unroll
            for (int nj = 0; nj < 4; nj++)
                out[(size_t)gm * 256 + colbase + nj * 16] =
                    (acc[mi][nj][r] - mean) * inv * gv[nj] + bbv[nj];
        }
    }
}

// ---------------- attention (wave-per-node, PAIR-EDGE fp8 k/v) + fused LN1 -----------
__global__ __launch_bounds__(128)
void att_agg_kernel(const __hip_bfloat16* __restrict__ qb,
                    const unsigned char* __restrict__ kv8,
                    const unsigned* __restrict__ offsets,
                    const unsigned* __restrict__ bpre,
                    const int* __restrict__ scol,
                    const __hip_bfloat16* __restrict__ xres,
                    const float* __restrict__ g, const float* __restrict__ bb,
                    __hip_bfloat16* __restrict__ xn) {
    int n = blockIdx.x * 2 + (threadIdx.x >> 6);
    if (n >= N_NODES) return;
    const int lam = threadIdx.x & 63;
    const int hl  = lam & 31;
    const int sel = lam >> 5;
    const unsigned hlb = hl * 16;
    unsigned beg = offsets[n] + bpre[n >> 8];
    unsigned end = (n + 1 == N_NODES) ? bpre[NB_SCAN]
                                      : offsets[n + 1] + bpre[(n + 1) >> 8];

    float qv[8];
    {
        uint4 u = *reinterpret_cast<const uint4*>(qb + (size_t)n * 256 + hl * 8);
        unpack_bf8(u, qv);
#pragma unroll
        for (int i = 0; i < 8; i++) qv[i] *= ATT_SCALE;
    }

    float acc[8] = {};
    float l = 0.f;

#define PAIR_BODY(W, VMUL)                                                      \
    {                                                                           \
        auto k01 = __builtin_amdgcn_cvt_pk_f32_fp8((int)(W).x, false);          \
        auto k23 = __builtin_amdgcn_cvt_pk_f32_fp8((int)(W).x, true);           \
        auto k45 = __builtin_amdgcn_cvt_pk_f32_fp8((int)(W).z, false);          \
        auto k67 = __builtin_amdgcn_cvt_pk_f32_fp8((int)(W).z, true);           \
        float sv = qv[0] * k01[0] + qv[1] * k01[1] + qv[2] * k23[0]             \
                 + qv[3] * k23[1] + qv[4] * k45[0] + qv[5] * k45[1]             \
                 + qv[6] * k67[0] + qv[7] * k67[1];                             \
        sv = dpp_add<0xB1>(sv);                                                 \
        sv = dpp_add<0x4E>(sv);                                                 \
        float pv = __expf(sv) * (VMUL);                                         \
        l += pv;                                                                \
        auto v01 = __builtin_amdgcn_cvt_pk_f32_fp8((int)(W).y, false);          \
        auto v23 = __builtin_amdgcn_cvt_pk_f32_fp8((int)(W).y, true);           \
        auto v45 = __builtin_amdgcn_cvt_pk_f32_fp8((int)(W).w, false);          \
        auto v67 = __builtin_amdgcn_cvt_pk_f32_fp8((int)(W).w, true);           \
        acc[0] += pv * v01[0]; acc[1] += pv * v01[1];                           \
        acc[2] += pv * v23[0]; acc[3] += pv * v23[1];                           \
        acc[4] += pv * v45[0]; acc[5] += pv * v45[1];                           \
        acc[6] += pv * v67[0]; acc[7] += pv * v67[1];                           \
    }

    unsigned e = beg;
    unsigned oA = 0, oB = 0, oC = 0, oD = 0;
    if (e + 8 <= end) {
        oA = ((unsigned)scol[e + sel])     << 9;
        oB = ((unsigned)scol[e + 2 + sel]) << 9;
        oC = ((unsigned)scol[e + 4 + sel]) << 9;
        oD = ((unsigned)scol[e + 6 + sel]) << 9;
    }
    while (e + 8 <= end) {
        uint4 wa = *reinterpret_cast<const uint4*>(kv8 + (oA + hlb));
        uint4 wb = *reinterpret_cast<const uint4*>(kv8 + (oB + hlb));
        uint4 wc = *reinterpret_cast<const uint4*>(kv8 + (oC + hlb));
        uint4 wd = *reinterpret_cast<const uint4*>(kv8 + (oD + hlb));
        e += 8;
        if (e + 8 <= end) {
            oA = ((unsigned)scol[e + sel])     << 9;
            oB = ((unsigned)scol[e + 2 + sel]) << 9;
            oC = ((unsigned)scol[e + 4 + sel]) << 9;
            oD = ((unsigned)scol[e + 6 + sel]) << 9;
        }
        PAIR_BODY(wa, 1.0f)
        PAIR_BODY(wb, 1.0f)
        PAIR_BODY(wc, 1.0f)
        PAIR_BODY(wd, 1.0f)
    }
    for (; e + 2 <= end; e += 2) {
        unsigned o0 = ((unsigned)scol[e + sel]) << 9;
        uint4 wa = *reinterpret_cast<const uint4*>(kv8 + (o0 + hlb));
        PAIR_BODY(wa, 1.0f)
    }
    if (e < end) {
        unsigned o0 = ((unsigned)scol[e]) << 9;
        uint4 wa = *reinterpret_cast<const uint4*>(kv8 + (o0 + hlb));
        PAIR_BODY(wa, sel ? 0.0f : 1.0f)
    }
#undef PAIR_BODY

    l += __shfl_xor(l, 32);
#pragma unroll
    for (int i = 0; i < 8; i++) acc[i] += __shfl_xor(acc[i], 32);

    float inv_l = (l > 0.f) ? 1.f / l : 0.f;

    float tv[8];
    {
        float xv[8];
        uint4 u = *reinterpret_cast<const uint4*>(xres + (size_t)n * D_MODEL + hl * 8);
        unpack_bf8(u, xv);
#pragma unroll
        for (int i = 0; i < 8; i++) tv[i] = acc[i] * inv_l + xv[i];
    }

    float s = 0.f, s2 = 0.f;
#pragma unroll
    for (int i = 0; i < 8; i++) { s += tv[i]; s2 += tv[i] * tv[i]; }
#pragma unroll
    for (int off = 1; off <= 16; off <<= 1) {
        s  += __shfl_xor(s, off);
        s2 += __shfl_xor(s2, off);
    }
    float mean = s * (1.f / (float)D_MODEL);
    float var  = s2 * (1.f / (float)D_MODEL) - mean * mean;
    float inv  = rsqrtf(var + LN_EPS);

    if (sel == 0) {
        const float4* gp = reinterpret_cast<const float4*>(g);
        const float4* bp = reinterpret_cast<const float4*>(bb);
        float4 g0 = gp[hl * 2], g1 = gp[hl * 2 + 1];
        float4 b0 = bp[hl * 2], b1 = bp[hl * 2 + 1];
        float gv[8] = {g0.x, g0.y, g0.z, g0.w, g1.x, g1.y, g1.z, g1.w};
        float bv[8] = {b0.x, b0.y, b0.z, b0.w, b1.x, b1.y, b1.z, b1.w};
        u16x8 o;
#pragma unroll
        for (int i = 0; i < 8; i++)
            o[i] = bfbits((tv[i] - mean) * inv * gv[i] + bv[i]);
        *reinterpret_cast<u16x8*>(xn + (size_t)n * D_MODEL + hl * 8) = o;
    }
}

extern "C" void kernel_launch(void* const* d_in, const int* in_sizes, int n_in,
                              void* d_out, int out_size, void* d_ws, size_t ws_size,
                              hipStream_t stream) {
    const float* x     = (const float*)d_in[0];
    const int*   ei    = (const int*)d_in[1];
    const float* w_qkv = (const float*)d_in[2];
    const float* b_qkv = (const float*)d_in[3];
    const float* ln1_g = (const float*)d_in[4];
    const float* ln1_b = (const float*)d_in[5];
    const float* ln2_g = (const float*)d_in[6];
    const float* ln2_b = (const float*)d_in[7];
    const float* w1    = (const float*)d_in[8];
    const float* b1    = (const float*)d_in[9];
    const float* w2    = (const float*)d_in[10];
    const float* b2    = (const float*)d_in[11];
    const int* rows = ei;
    const int* cols = ei + E_EDGES;

    // workspace layout (bytes), total < 179,200,000 (known-good footprint):
    //   [0,          25,600,000)  qb  bf16 N*256 } dead after att_agg;
    //   [25,600,000, 51,200,000)  kv8 fp8  N*512 } region [0,102.4e6) reused as hbuf
    //   [102,400,000,128,000,000) xb bf16 N*256 (live through att_agg: residual src)
    //   [128,000,000,128,393,216) wtq bf16 768x256 (perm cols)
    //   [128,400,000,128,924,288) wt1 bf16 1024x256 (perm cols)
    //   [129,000,000,129,524,288) wt2 bf16 256x1024
    //   [129,600,000,129,800,000) counts u32 N
    //   [129,800,000,130,000,004) offsets u32 N+1 (block-local prefixes)
    //   [130,000,008,130,200,008) cursor u32 N
    //   [130,200,008,133,400,008) scol i32 E
    //   [133,400,008,133,401,032) bsum u32 256 (bsum[200] = scan ticket counter)
    //   [133,401,032,133,402,060) bpre u32 257
    //   [133,500,000,133,503,072) bqp f32 768 (perm qkv bias)
    //   [133,510,000,133,514,096) b1p f32 1024 (perm ffn1 bias)
    //   [153,600,000,179,200,000) xn bf16 N*256
    char* ws = (char*)d_ws;
    __hip_bfloat16* qb      = (__hip_bfloat16*)(ws + 0);
    unsigned char*  kv8     = (unsigned char*)(ws + 25600000);
    __hip_bfloat16* hbuf    = (__hip_bfloat16*)(ws + 0);
    __hip_bfloat16* xb      = (__hip_bfloat16*)(ws + 102400000);
    __hip_bfloat16* wtq     = (__hip_bfloat16*)(ws + 128000000);
    __hip_bfloat16* wt1     = (__hip_bfloat16*)(ws + 128400000);
    __hip_bfloat16* wt2     = (__hip_bfloat16*)(ws + 129000000);
    unsigned*       counts  = (unsigned*)(ws + 129600000);
    unsigned*       offsets = (unsigned*)(ws + 129800000);
    unsigned*       cursor  = (unsigned*)(ws + 130000008);
    int*            scol    = (int*)(ws + 130200008);
    unsigned*       bsum    = (unsigned*)(ws + 133400008);
    unsigned*       bpre    = (unsigned*)(ws + 133401032);
    float*          bqp     = (float*)(ws + 133500000);
    float*          b1p     = (float*)(ws + 133510000);
    __hip_bfloat16* xn      = (__hip_bfloat16*)(ws + 153600000);
    unsigned*       scnt    = bsum + 200;    // unused bsum slot (only 196 blocks)

    // zero counts (stream-ordered before prep's atomics); cursor zeroed in scan_blk
    hipMemsetAsync(counts, 0, N_NODES * sizeof(unsigned), stream);

    // prep: edge-count + x->bf16 + wtq/bqp perms + zero scan ticket
    prep_kernel<<<(PREP_TOT + 255) / 256, 256, 0, stream>>>(
        rows, counts, x, (unsigned short*)xb, w_qkv, wtq, b_qkv, bqp, scnt);

    // CSR scan: single kernel (StreamScan) + cursor zeroing
    scan_blk_kernel<<<NB_SCAN, 256, 0, stream>>>(counts, offsets, bsum, bpre, scnt, cursor);

    // MEGA: roles striped 1:2 (aux:gemm) through the grid for true co-residency
    mega_kernel<<<NB_MEGA, 256, 0, stream>>>(
        xb, wtq, bqp, qb, kv8,
        rows, cols, offsets, bpre, cursor, scol,
        w1, wt1, w2, wt2, b1, b1p, N_NODES);

    // attention (pair-edge, 8-edge pipelined, DPP reduce, bf16 residual) + LN1 -> xn
    att_agg_kernel<<<(N_NODES + 1) / 2, 128, 0, stream>>>(qb, kv8, offsets, bpre, scol,
                                                          xb, ln1_g, ln1_b, xn);

    // hbuf = relu(xn @ wt1^T + b1p)  — 128x256-tile 8-wave 2-phase (ffn2 schedule)
    ffn1_kernel<<<dim3(F_FFN / 256, (N_NODES + 127) / 128), 512, 0, stream>>>(
        xn, wt1, b1p, hbuf, N_NODES);

    // d_out = LN2(hbuf @ wt2^T + b2 + xn)   (fused, f32 out; 2-phase 40KB dbuf)
    ffn2_ln_kernel<<<(N_NODES + 63) / 64, 512, 0, stream>>>(hbuf, wt2, b2, xn, ln2_g, ln2_b,
                                                            (float*)d_out, N_NODES);
}

// Round 14
// 398.795 us; speedup vs baseline: 1.0168x; 1.0168x over previous
//
#include <hip/hip_runtime.h>
#include <hip/hip_bf16.h>

#define N_NODES 50000
#define E_EDGES 800000
#define D_MODEL 256
#define H_HEADS 8
#define HDIM    32
#define F_FFN   1024
#define ATT_SCALE 0.0625f   // 256^-0.5
#define LN_EPS  1e-5f
#define NB_SCAN 196         // ceil(N_NODES/256)

typedef __attribute__((ext_vector_type(8))) short bf16x8;
typedef __attribute__((ext_vector_type(8))) unsigned short u16x8;
typedef __attribute__((ext_vector_type(4))) float f32x4;

__device__ __forceinline__ float bf2f(__hip_bfloat16 v) { return __bfloat162float(v); }
__device__ __forceinline__ __hip_bfloat16 f2bf(float v) { return __float2bfloat16(v); }
__device__ __forceinline__ unsigned short bfbits(float f) {
    __hip_bfloat16 h = __float2bfloat16(f);
    return *reinterpret_cast<unsigned short*>(&h);
}

// unpack 8 consecutive bf16 (16B aligned) -> 8 floats
__device__ __forceinline__ void unpack_bf8(uint4 u, float* f) {
    f[0] = __uint_as_float(u.x << 16); f[1] = __uint_as_float(u.x & 0xFFFF0000u);
    f[2] = __uint_as_float(u.y << 16); f[3] = __uint_as_float(u.y & 0xFFFF0000u);
    f[4] = __uint_as_float(u.z << 16); f[5] = __uint_as_float(u.z & 0xFFFF0000u);
    f[6] = __uint_as_float(u.w << 16); f[7] = __uint_as_float(u.w & 0xFFFF0000u);
}

// VALU-only quad reduce: v + dpp_perm(v). CTRL 0xB1 = xor1, 0x4E = xor2 (within quad).
template<int CTRL>
__device__ __forceinline__ float dpp_add(float v) {
    int t = __builtin_amdgcn_update_dpp(0, __float_as_int(v), CTRL, 0xF, 0xF, true);
    return v + __int_as_float(t);
}

// async global->LDS, 16B per lane; LDS dest must be wave-uniform base (+lane*16 implicit)
__device__ __forceinline__ void load_lds16(const void* g, void* l) {
    __builtin_amdgcn_global_load_lds(
        (const __attribute__((address_space(1))) unsigned*)g,
        (__attribute__((address_space(3))) unsigned*)l, 16, 0, 0);
}

#define WAITV(N) asm volatile("s_waitcnt vmcnt(" #N ")" ::: "memory")
#define SBAR()   { __builtin_amdgcn_sched_barrier(0); __builtin_amdgcn_s_barrier(); \
                   __builtin_amdgcn_sched_barrier(0); }

// Column permutation (16x4 transpose within each 64-col block):
//   gemm perm-col p holds logical col T(p) = (p&~63) + ((p&15)<<2) + ((p>>4)&3)
// The packed epilogue stores each lane's 4 nj-values at contiguous logical cols ->
// outputs land in ORIGINAL logical order (att/wt2 consumers unchanged).

// ---------------- prep (block roles): edge-count + cvt_x + TILED wtq + bqp -----------
// counts is zeroed by hipMemsetAsync BEFORE this kernel; cursor zeroed in scan_blk.
// wtq transpose is 64x64 LDS-tiled (coalesced both sides; was 196k strided reads).
#define NB_PE    ((E_EDGES + 255) / 256)      // 3125
#define NB_PX    12500                        // 3.2M float4 / 256
#define NB_PWQ   48                           // 4 k-tiles x 12 col-tiles of 64x64
#define NB_PREP  (NB_PE + NB_PX + NB_PWQ + 1)
__global__ void prep_kernel(const int* __restrict__ rows, unsigned* __restrict__ counts,
                            const float* __restrict__ x, unsigned short* __restrict__ xb,
                            const float* __restrict__ wq, __hip_bfloat16* __restrict__ wtq,
                            const float* __restrict__ bq, float* __restrict__ bqp,
                            unsigned* __restrict__ scnt) {
    __shared__ float tl[64 * 65];
    const int bid = blockIdx.x, t = threadIdx.x;
    if (bid < NB_PE) {
        int e = bid * 256 + t;
        if (e < E_EDGES) atomicAdd(&counts[rows[e]], 1u);
        return;
    }
    if (bid < NB_PE + NB_PX) {
        int i = (bid - NB_PE) * 256 + t;      // float4 index, < 3.2M exactly
        float4 v = reinterpret_cast<const float4*>(x)[i];
        ushort4 o;
        o.x = bfbits(v.x); o.y = bfbits(v.y); o.z = bfbits(v.z); o.w = bfbits(v.w);
        reinterpret_cast<ushort4*>(xb)[i] = o;
        return;
    }
    if (bid < NB_PE + NB_PX + NB_PWQ) {
        // tiled transpose wq[256][768] -> wtq[perm-n][k] (bf16)
        int aid = bid - NB_PE - NB_PX;
        int kt = aid / 12, ct = aid % 12;
        int k0 = kt * 64, c0 = ct * 64;
#pragma unroll
        for (int r = 0; r < 16; ++r) {        // coalesced row loads
            int idx = r * 256 + t;
            int kk = idx >> 6, cc = idx & 63;
            tl[kk * 65 + cc] = wq[(size_t)(k0 + kk) * 768 + c0 + cc];
        }
        __syncthreads();
#pragma unroll
        for (int r = 0; r < 16; ++r) {        // per source col -> perm dest row
            int idx = r * 256 + t;
            int nl = idx >> 6, kk = idx & 63;
            int co = c0 + nl;
            int g = co / 96, r96 = co % 96;
            int s = r96 >> 5, r32 = r96 & 31;
            int d = g * 32 + r32;                                      // logical dim
            int prel = (d & 192) | ((d & 3) << 4) | ((d >> 2) & 15);   // T^-1(d)
            int n = s * 256 + prel;                                    // perm col
            wtq[(size_t)n * 256 + k0 + kk] = f2bf(tl[kk * 65 + nl]);
        }
        return;
    }
    // last block: bqp perm + scnt
    for (int j = t; j < 768; j += 256) {
        int s = j >> 8, prel = j & 255;
        int d = (prel & 192) + ((prel & 15) << 2) + ((prel >> 4) & 3);
        bqp[j] = bq[(d >> 5) * 96 + s * 32 + (d & 31)];
    }
    if (t == 0) *scnt = 0u;
}

// ---------------- single-kernel CSR scan (StreamScan) + cursor zeroing ---------------
__global__ void scan_blk_kernel(const unsigned* __restrict__ counts,
                                unsigned* __restrict__ offs, unsigned* __restrict__ bsum,
                                unsigned* __restrict__ bpre, unsigned* __restrict__ scnt,
                                unsigned* __restrict__ cursor) {
    __shared__ unsigned sh[256];
    __shared__ unsigned lastflag;
    int t = threadIdx.x;
    int i = blockIdx.x * 256 + t;
    unsigned v = (i < N_NODES) ? counts[i] : 0u;
    if (i < N_NODES) cursor[i] = 0u;             // folded memset
    sh[t] = v;
    __syncthreads();
#pragma unroll
    for (int off = 1; off < 256; off <<= 1) {
        unsigned u = (t >= off) ? sh[t - off] : 0u;
        __syncthreads();
        sh[t] += u;
        __syncthreads();
    }
    if (i < N_NODES) offs[i] = sh[t] - v;
    if (t == 255) {
        bsum[blockIdx.x] = sh[255];
        __threadfence();                         // release: bsum visible device-wide
        unsigned ticket = atomicAdd(scnt, 1u);
        lastflag = (ticket == NB_SCAN - 1) ? 1u : 0u;
    }
    __syncthreads();
    if (lastflag) {                              // last block does the 196-entry scan
        __threadfence();                         // acquire side
        unsigned v2 = (t < NB_SCAN) ? atomicAdd(&bsum[t], 0u) : 0u;  // device-scope read
        __syncthreads();
        sh[t] = v2;
        __syncthreads();
#pragma unroll
        for (int off = 1; off < 256; off <<= 1) {
            unsigned u = (t >= off) ? sh[t - off] : 0u;
            __syncthreads();
            sh[t] += u;
            __syncthreads();
        }
        if (t < NB_SCAN) bpre[t] = sh[t] - v2;
        if (t == NB_SCAN - 1) bpre[NB_SCAN] = sh[t];
    }
}

// ---------------- MEGA kernel: roles STRIPED through the grid ------------------------
// Aux blocks interleaved 1:2 with gemm blocks so every dispatch window mixes
// latency-bound scatter with MFMA-bound gemm on each CU.
#define NB_QKV_X 6                       // 768/128
#define NB_QKV_Y ((N_NODES + 127) / 128) // 391
#define NB_QKV   (NB_QKV_X * NB_QKV_Y)   // 2346
#define NB_TRANS 128
#define NB_SCAT2 1024
#define NB_AUXR  (NB_TRANS + 1 + NB_SCAT2)   // 1153
#define NB_MEGA  (NB_QKV + NB_AUXR)          // 3499
__global__ __launch_bounds__(256)
void mega_kernel(const __hip_bfloat16* __restrict__ A,      // xb M x 256
                 const __hip_bfloat16* __restrict__ Wt,     // wtq 768 x 256 (perm)
                 const float* __restrict__ bias,            // bqp
                 __hip_bfloat16* __restrict__ qb,
                 unsigned char* __restrict__ kv8,
                 const int* __restrict__ rows, const int* __restrict__ cols,
                 const unsigned* __restrict__ offsets, const unsigned* __restrict__ bpre,
                 unsigned* __restrict__ cursor, int* __restrict__ scol,
                 const float* __restrict__ w1, __hip_bfloat16* __restrict__ wt1,
                 const float* __restrict__ w2, __hip_bfloat16* __restrict__ wt2,
                 const float* __restrict__ b1, float* __restrict__ b1p,
                 int M) {
    __shared__ short Al[3][128 * 32];
    __shared__ short Bl[3][128 * 32];
    const int bid = blockIdx.x;
    const int t = threadIdx.x;

    const bool is_aux = (bid % 3 == 2) && (bid / 3 < NB_AUXR);
    if (is_aux) {
        const int aid = bid / 3;
        if (aid < NB_TRANS) {
            // ---- 64x64 LDS-tiled transpose role ----
            float* tl = reinterpret_cast<float*>(&Al[0][0]);   // [64][65] f32 = 16.6 KB
            const float* src; __hip_bfloat16* dst;
            int k0, c0, W, KD; bool perm;
            if (aid < 64) {      // w1: 256 k-rows x 1024 cols -> wt1[n*256+k] (perm)
                int kt = aid >> 4, ct = aid & 15;
                k0 = kt * 64; c0 = ct * 64; W = 1024; KD = 256;
                src = w1; dst = wt1; perm = true;
            } else {             // w2: 1024 k-rows x 256 cols -> wt2[n*1024+k]
                int rb2 = aid - 64;
                int kt = rb2 >> 2, ct = rb2 & 3;
                k0 = kt * 64; c0 = ct * 64; W = 256; KD = 1024;
                src = w2; dst = wt2; perm = false;
            }
#pragma unroll
            for (int r = 0; r < 16; ++r) {      // coalesced row loads
                int idx = r * 256 + t;
                int kk = idx >> 6, cc = idx & 63;
                tl[kk * 65 + cc] = src[(size_t)(k0 + kk) * W + c0 + cc];
            }
            __syncthreads();
#pragma unroll
            for (int r = 0; r < 16; ++r) {      // coalesced column stores (along k)
                int idx = r * 256 + t;
                int nl = idx >> 6, kk = idx & 63;
                int cl = perm ? (((nl & 15) << 2) + ((nl >> 4) & 3)) : nl;  // T(nl)
                dst[(size_t)(c0 + nl) * KD + k0 + kk] = f2bf(tl[kk * 65 + cl]);
            }
            return;
        }
        if (aid == NB_TRANS) {
            // ---- b1p role ----
            for (int j = t; j < 1024; j += 256) {
                int f = (j & ~63) + ((j & 15) << 2) + ((j >> 4) & 3);
                b1p[j] = b1[f];
            }
            return;
        }
        // ---- scatter role: grid-stride over edges ----
        int sb = aid - NB_TRANS - 1;            // 0..1023
        for (int e = sb * 256 + t; e < E_EDGES; e += NB_SCAT2 * 256) {
            int r = rows[e];
            unsigned idx = atomicAdd(&cursor[r], 1u);
            scol[offsets[r] + bpre[r >> 8] + idx] = cols[e];
        }
        return;
    }

    // ---- qkv gemm role: dense gemm_id over non-aux bids ----
    int gemm_id = (bid < 3 * NB_AUXR) ? (bid - (bid + 1) / 3) : (bid - NB_AUXR);

    const int wave = t >> 6, lane = t & 63;
    unsigned flat = (unsigned)gemm_id;
    unsigned nwg = NB_QKV;
    unsigned q8 = nwg >> 3, r8 = nwg & 7;
    unsigned xcd = flat & 7, pos = flat >> 3;
    unsigned wg = (xcd < r8) ? (xcd * (q8 + 1) + pos)
                             : (r8 * (q8 + 1) + (xcd - r8) * q8 + pos);
    const int m0 = (int)(wg / NB_QKV_X) * 128;
    const int n0 = (int)(wg % NB_QKV_X) * 128;

    const int wr = wave >> 1, wc = wave & 1;
    const int srow = lane >> 2;
    const int skp  = (lane & 3) ^ ((lane >> 3) & 3);
    const int c0 = wave * 2;
    int ar0 = m0 + c0 * 16 + srow;      if (ar0 >= M) ar0 = M - 1;
    int ar1 = m0 + c0 * 16 + 16 + srow; if (ar1 >= M) ar1 = M - 1;
    const __hip_bfloat16* ga0 = A + (size_t)ar0 * 256 + skp * 8;
    const __hip_bfloat16* ga1 = A + (size_t)ar1 * 256 + skp * 8;
    const __hip_bfloat16* gb0 = Wt + (size_t)(n0 + c0 * 16 + srow) * 256 + skp * 8;
    const __hip_bfloat16* gb1 = Wt + (size_t)(n0 + c0 * 16 + 16 + srow) * 256 + skp * 8;

    const int lh = lane & 15, q = lane >> 4;
    const int qs = q ^ ((lane >> 1) & 3);
    const short* faB = &Al[0][(wr * 64 + lh) * 32 + qs * 8];
    const short* fbB = &Bl[0][(wc * 64 + lh) * 32 + qs * 8];

    f32x4 acc[4][4] = {};

#define GSTAGE(B)                                    \
    load_lds16(ga0, &Al[B][c0 * 512]);               \
    load_lds16(ga1, &Al[B][c0 * 512 + 512]);         \
    load_lds16(gb0, &Bl[B][c0 * 512]);               \
    load_lds16(gb1, &Bl[B][c0 * 512 + 512]);         \
    ga0 += 32; ga1 += 32; gb0 += 32; gb1 += 32;

#define GSTEP(FA, FB)                                                       \
    {                                                                       \
        bf16x8 af[4], bfr[4];                                               \
        _Pragma("unroll")                                                   \
        for (int i = 0; i < 4; i++) {                                       \
            af[i]  = *reinterpret_cast<const bf16x8*>((FA) + i * 16 * 32);  \
            bfr[i] = *reinterpret_cast<const bf16x8*>((FB) + i * 16 * 32);  \
        }                                                                   \
        _Pragma("unroll")                                                   \
        for (int mi = 0; mi < 4; mi++)                                      \
            _Pragma("unroll")                                               \
            for (int nj = 0; nj < 4; nj++)                                  \
                acc[mi][nj] = __builtin_amdgcn_mfma_f32_16x16x32_bf16(      \
                    af[mi], bfr[nj], acc[mi][nj], 0, 0, 0);                 \
    }

    GSTAGE(0)
    GSTAGE(1)
#pragma unroll
    for (int s = 0; s < 8; ++s) {
        if (s < 7) { WAITV(4); } else { WAITV(0); }
        SBAR();
        if (s + 2 < 8) {
            switch ((s + 2) % 3) {
                case 0: { GSTAGE(0) } break;
                case 1: { GSTAGE(1) } break;
                default: { GSTAGE(2) } break;
            }
        }
        const short* fa = faB + (s % 3) * 4096;
        const short* fb = fbB + (s % 3) * 4096;
        GSTEP(fa, fb)
    }
#undef GSTAGE
#undef GSTEP

    const int B = n0 + wc * 64;
    const int gnbase = B + lh;
    float bv[4];
#pragma unroll
    for (int nj = 0; nj < 4; nj++) bv[nj] = bias[gnbase + nj * 16];

    const int sec = B >> 8;                       // 0=q,1=k,2=v (block-uniform)
    const int c = ((B & 255) >> 6) * 16 + lh;     // chunk index [0,64)
#pragma unroll
    for (int mi = 0; mi < 4; mi++) {
        int gmb = m0 + wr * 64 + mi * 16 + q * 4;
#pragma unroll
        for (int r = 0; r < 4; r++) {
            int gm = gmb + r;
            if (gm >= M) continue;
            float v0 = acc[mi][0][r] + bv[0];
            float v1 = acc[mi][1][r] + bv[1];
            float v2 = acc[mi][2][r] + bv[2];
            float v3 = acc[mi][3][r] + bv[3];
            if (sec == 0) {
                ushort4 o;
                o.x = bfbits(v0); o.y = bfbits(v1); o.z = bfbits(v2); o.w = bfbits(v3);
                *reinterpret_cast<ushort4*>(qb + (size_t)gm * 256 + c * 4) = o;
            } else {
                unsigned u = (unsigned)__builtin_amdgcn_cvt_pk_fp8_f32(v0, v1, 0, false);
                u = (unsigned)__builtin_amdgcn_cvt_pk_fp8_f32(v2, v3, (int)u, true);
                *reinterpret_cast<unsigned*>(
                    kv8 + (size_t)gm * 512 + c * 8 + (sec == 1 ? 0 : 4)) = u;
            }
        }
    }
}

// ---------------- MFMA GEMM (ffn1): out = relu(A @ Wt^T + bias), packed bf16 ---------
template<bool RELU, int EPI, int KT>
__global__ __launch_bounds__(256)
void mfma_gemm(const __hip_bfloat16* __restrict__ A,
               const __hip_bfloat16* __restrict__ Wt,
               const float* __restrict__ bias,
               __hip_bfloat16* __restrict__ outp,
               int M, int Ncols) {
    __shared__ short Al[3][128 * 32];
    __shared__ short Bl[3][128 * 32];
    const int t = threadIdx.x;
    const int wave = t >> 6, lane = t & 63;

    unsigned flat = blockIdx.y * gridDim.x + blockIdx.x;
    unsigned nwg = gridDim.x * gridDim.y;
    unsigned q8 = nwg >> 3, r8 = nwg & 7;
    unsigned xcd = flat & 7, pos = flat >> 3;
    unsigned wg = (xcd < r8) ? (xcd * (q8 + 1) + pos)
                             : (r8 * (q8 + 1) + (xcd - r8) * q8 + pos);
    const int m0 = (int)(wg / gridDim.x) * 128;
    const int n0 = (int)(wg % gridDim.x) * 128;

    const int wr = wave >> 1, wc = wave & 1;
    const int srow = lane >> 2;
    const int skp  = (lane & 3) ^ ((lane >> 3) & 3);
    const int c0 = wave * 2;
    int ar0 = m0 + c0 * 16 + srow;      if (ar0 >= M) ar0 = M - 1;
    int ar1 = m0 + c0 * 16 + 16 + srow; if (ar1 >= M) ar1 = M - 1;
    const __hip_bfloat16* ga0 = A + (size_t)ar0 * KT + skp * 8;
    const __hip_bfloat16* ga1 = A + (size_t)ar1 * KT + skp * 8;
    const __hip_bfloat16* gb0 = Wt + (size_t)(n0 + c0 * 16 + srow) * KT + skp * 8;
    const __hip_bfloat16* gb1 = Wt + (size_t)(n0 + c0 * 16 + 16 + srow) * KT + skp * 8;

    const int lh = lane & 15, q = lane >> 4;
    const int qs = q ^ ((lane >> 1) & 3);
    const short* faB = &Al[0][(wr * 64 + lh) * 32 + qs * 8];
    const short* fbB = &Bl[0][(wc * 64 + lh) * 32 + qs * 8];

    f32x4 acc[4][4] = {};

#define GSTAGE(B)                                    \
    load_lds16(ga0, &Al[B][c0 * 512]);               \
    load_lds16(ga1, &Al[B][c0 * 512 + 512]);         \
    load_lds16(gb0, &Bl[B][c0 * 512]);               \
    load_lds16(gb1, &Bl[B][c0 * 512 + 512]);         \
    ga0 += 32; ga1 += 32; gb0 += 32; gb1 += 32;

#define GSTEP(FA, FB)                                                       \
    {                                                                       \
        bf16x8 af[4], bfr[4];                                               \
        _Pragma("unroll")                                                   \
        for (int i = 0; i < 4; i++) {                                       \
            af[i]  = *reinterpret_cast<const bf16x8*>((FA) + i * 16 * 32);  \
            bfr[i] = *reinterpret_cast<const bf16x8*>((FB) + i * 16 * 32);  \
        }                                                                   \
        _Pragma("unroll")                                                   \
        for (int mi = 0; mi < 4; mi++)                                      \
            _Pragma("unroll")                                               \
            for (int nj = 0; nj < 4; nj++)                                  \
                acc[mi][nj] = __builtin_amdgcn_mfma_f32_16x16x32_bf16(      \
                    af[mi], bfr[nj], acc[mi][nj], 0, 0, 0);                 \
    }

    constexpr int ns = KT >> 5;
    GSTAGE(0)
    GSTAGE(1)
#pragma unroll
    for (int s = 0; s < ns; ++s) {
        if (s < ns - 1) { WAITV(4); } else { WAITV(0); }
        SBAR();
        if (s + 2 < ns) {
            switch ((s + 2) % 3) {
                case 0: { GSTAGE(0) } break;
                case 1: { GSTAGE(1) } break;
                default: { GSTAGE(2) } break;
            }
        }
        const short* fa = faB + (s % 3) * 4096;
        const short* fb = fbB + (s % 3) * 4096;
        GSTEP(fa, fb)
    }
#undef GSTAGE
#undef GSTEP

    const int B = n0 + wc * 64;
    const int gnbase = B + lh;
    float bv[4];
#pragma unroll
    for (int nj = 0; nj < 4; nj++) bv[nj] = bias[gnbase + nj * 16];

    const int cb = B + lh * 4;                    // logical col base (T-perm)
#pragma unroll
    for (int mi = 0; mi < 4; mi++) {
        int gmb = m0 + wr * 64 + mi * 16 + q * 4;
#pragma unroll
        for (int r = 0; r < 4; r++) {
            int gm = gmb + r;
            if (gm >= M) continue;
            float v0 = acc[mi][0][r] + bv[0];
            float v1 = acc[mi][1][r] + bv[1];
            float v2 = acc[mi][2][r] + bv[2];
            float v3 = acc[mi][3][r] + bv[3];
            if (RELU) {
                v0 = fmaxf(v0, 0.f); v1 = fmaxf(v1, 0.f);
                v2 = fmaxf(v2, 0.f); v3 = fmaxf(v3, 0.f);
            }
            ushort4 o;
            o.x = bfbits(v0); o.y = bfbits(v1); o.z = bfbits(v2); o.w = bfbits(v3);
            *reinterpret_cast<ushort4*>(outp + (size_t)gm * Ncols + cb) = o;
        }
    }
}

// ---------------- ffn2 + fused LN2: out = LN(hbuf @ wt2^T + b2 + xn) ------------------
// 64 x 256 tile, 512 threads = 8 waves (2x4 of 32x64), K=1024, BK=32,
// 2-phase double-buffered LDS (40 KB), single __syncthreads per K-step.
__global__ __launch_bounds__(512)
void ffn2_ln_kernel(const __hip_bfloat16* __restrict__ A,    // M x 1024
                    const __hip_bfloat16* __restrict__ Wt,   // 256 x 1024
                    const float* __restrict__ bias,
                    const __hip_bfloat16* __restrict__ resid,// M x 256
                    const float* __restrict__ g, const float* __restrict__ bb,
                    float* __restrict__ out, int M) {
    __shared__ short LDS[2][(64 + 256) * 32];   // A at [0,2048), B at [2048,10240)
    const int t = threadIdx.x;
    const int wave = t >> 6, lane = t & 63;
    const int m0 = blockIdx.x * 64;
    const int wr = wave >> 2, wc = wave & 3;

    const int srow = lane >> 2;
    const int skp  = (lane & 3) ^ ((lane >> 3) & 3);

    const __hip_bfloat16* gsrc0; int loff0;
    const __hip_bfloat16* gsrc1; int loff1;
    const __hip_bfloat16* gsrc2; int loff2;
    {
#define STAGE_INIT(GS, LO, C)                                            \
        if ((C) < 4) {                                                   \
            int r_ = m0 + (C) * 16 + srow; if (r_ >= M) r_ = M - 1;      \
            GS = A + (size_t)r_ * 1024 + skp * 8;                        \
            LO = (C) * 512;                                              \
        } else {                                                         \
            GS = Wt + (size_t)(((C) - 4) * 16 + srow) * 1024 + skp * 8;  \
            LO = 2048 + ((C) - 4) * 512;                                 \
        }
        STAGE_INIT(gsrc0, loff0, wave)
        STAGE_INIT(gsrc1, loff1, wave + 8)
        int c2 = (wave < 4) ? wave + 16 : 16;
        STAGE_INIT(gsrc2, loff2, c2)
#undef STAGE_INIT
    }

    const int lh = lane & 15, q = lane >> 4;
    const int qs = q ^ ((lane >> 1) & 3);
    const short* fa0 = &LDS[0][(wr * 32 + lh) * 32 + qs * 8];
    const short* fb0 = &LDS[0][2048 + (wc * 64 + lh) * 32 + qs * 8];
    const short* fa1 = &LDS[1][(wr * 32 + lh) * 32 + qs * 8];
    const short* fb1 = &LDS[1][2048 + (wc * 64 + lh) * 32 + qs * 8];

    f32x4 acc[2][4] = {};

#define FFN2_STAGE(BUF)                                      \
    load_lds16(gsrc0, &LDS[BUF][loff0]);                     \
    load_lds16(gsrc1, &LDS[BUF][loff1]);                     \
    if (wave < 4) load_lds16(gsrc2, &LDS[BUF][loff2]);       \
    gsrc0 += 32; gsrc1 += 32; gsrc2 += 32;

#define FFN2_STEP(FA, FB)                                                   \
    {                                                                       \
        bf16x8 af[2], bfr[4];                                               \
        _Pragma("unroll")                                                   \
        for (int i = 0; i < 2; i++)                                         \
            af[i] = *reinterpret_cast<const bf16x8*>((FA) + i * 16 * 32);   \
        _Pragma("unroll")                                                   \
        for (int i = 0; i < 4; i++)                                         \
            bfr[i] = *reinterpret_cast<const bf16x8*>((FB) + i * 16 * 32);  \
        _Pragma("unroll")                                                   \
        for (int mi = 0; mi < 2; mi++)                                      \
            _Pragma("unroll")                                               \
            for (int nj = 0; nj < 4; nj++)                                  \
                acc[mi][nj] = __builtin_amdgcn_mfma_f32_16x16x32_bf16(      \
                    af[mi], bfr[nj], acc[mi][nj], 0, 0, 0);                 \
    }

    FFN2_STAGE(0)
    __syncthreads();

    for (int s = 0; s < 32; s += 2) {
        FFN2_STAGE(1)
        FFN2_STEP(fa0, fb0)
        __syncthreads();
        if (s < 30) { FFN2_STAGE(0) }
        FFN2_STEP(fa1, fb1)
        __syncthreads();
    }
#undef FFN2_STAGE
#undef FFN2_STEP

    const int colbase = wc * 64 + lh;
    float bv[4], gv[4], bbv[4];
#pragma unroll
    for (int nj = 0; nj < 4; nj++) {
        bv[nj]  = bias[colbase + nj * 16];
        gv[nj]  = g[colbase + nj * 16];
        bbv[nj] = bb[colbase + nj * 16];
    }

    float ps[2][4], pq[2][4];
#pragma unroll
    for (int mi = 0; mi < 2; mi++) {
#pragma unroll
        for (int r = 0; r < 4; r++) {
            int gm = m0 + wr * 32 + mi * 16 + q * 4 + r;
            int rgm = (gm < M) ? gm : M - 1;
            float s = 0.f, s2 = 0.f;
#pragma unroll
            for (int nj = 0; nj < 4; nj++) {
                float v = acc[mi][nj][r] + bv[nj]
                        + bf2f(resid[(size_t)rgm * 256 + colbase + nj * 16]);
                acc[mi][nj][r] = v;
                s += v; s2 += v * v;
            }
            ps[mi][r] = s; pq[mi][r] = s2;
        }
    }
#pragma unroll
    for (int off = 1; off <= 8; off <<= 1) {
#pragma unroll
        for (int mi = 0; mi < 2; mi++)
#pragma unroll
            for (int r = 0; r < 4; r++) {
                ps[mi][r] += __shfl_xor(ps[mi][r], off);
                pq[mi][r] += __shfl_xor(pq[mi][r], off);
            }
    }
    float* rs = (float*)(&LDS[0][0]);   // [64][4]
    float* rq = rs + 256;
    if (lh == 0) {
#pragma unroll
        for (int mi = 0; mi < 2; mi++)
#pragma unroll
            for (int r = 0; r < 4; r++) {
                int m = wr * 32 + mi * 16 + q * 4 + r;
                rs[m * 4 + wc] = ps[mi][r];
                rq[m * 4 + wc] = pq[mi][r];
            }
    }
    __syncthreads();

#pragma unroll
    for (int mi = 0; mi < 2; mi++) {
#pragma unroll
        for (int r = 0; r < 4; r++) {
            int m = wr * 32 + mi * 16 + q * 4 + r;
            int gm = m0 + m;
            if (gm >= M) continue;
            float4 rsv = *reinterpret_cast<const float4*>(&rs[m * 4]);
            float4 rqv = *reinterpret_cast<const float4*>(&rq[m * 4]);
            float S  = (rsv.x + rsv.y) + (rsv.z + rsv.w);
            float S2 = (rqv.x + rqv.y) + (rqv.z + rqv.w);
            float mean = S * (1.f / (float)D_MODEL);
            float var  = S2 * (1.f / (float)D_MODEL) - mean * mean;
            float inv  = rsqrtf(var + LN_EPS);
#pragma unroll
            for (int nj = 0; nj < 4; nj++)
                out[(size_t)gm * 256 + colbase + nj * 16] =
                    (acc[mi][nj][r] - mean) * inv * gv[nj] + bbv[nj];
        }
    }
}

// ---------------- attention (wave-per-node, PAIR-EDGE fp8 k/v) + fused LN1 -----------
__global__ __launch_bounds__(128)
void att_agg_kernel(const __hip_bfloat16* __restrict__ qb,
                    const unsigned char* __restrict__ kv8,
                    const unsigned* __restrict__ offsets,
                    const unsigned* __restrict__ bpre,
                    const int* __restrict__ scol,
                    const __hip_bfloat16* __restrict__ xres,
                    const float* __restrict__ g, const float* __restrict__ bb,
                    __hip_bfloat16* __restrict__ xn) {
    int n = blockIdx.x * 2 + (threadIdx.x >> 6);
    if (n >= N_NODES) return;
    const int lam = threadIdx.x & 63;
    const int hl  = lam & 31;
    const int sel = lam >> 5;
    const unsigned hlb = hl * 16;
    unsigned beg = offsets[n] + bpre[n >> 8];
    unsigned end = (n + 1 == N_NODES) ? bpre[NB_SCAN]
                                      : offsets[n + 1] + bpre[(n + 1) >> 8];

    float qv[8];
    {
        uint4 u = *reinterpret_cast<const uint4*>(qb + (size_t)n * 256 + hl * 8);
        unpack_bf8(u, qv);
#pragma unroll
        for (int i = 0; i < 8; i++) qv[i] *= ATT_SCALE;
    }

    float acc[8] = {};
    float l = 0.f;

#define PAIR_BODY(W, VMUL)                                                      \
    {                                                                           \
        auto k01 = __builtin_amdgcn_cvt_pk_f32_fp8((int)(W).x, false);          \
        auto k23 = __builtin_amdgcn_cvt_pk_f32_fp8((int)(W).x, true);           \
        auto k45 = __builtin_amdgcn_cvt_pk_f32_fp8((int)(W).z, false);          \
        auto k67 = __builtin_amdgcn_cvt_pk_f32_fp8((int)(W).z, true);           \
        float sv = qv[0] * k01[0] + qv[1] * k01[1] + qv[2] * k23[0]             \
                 + qv[3] * k23[1] + qv[4] * k45[0] + qv[5] * k45[1]             \
                 + qv[6] * k67[0] + qv[7] * k67[1];                             \
        sv = dpp_add<0xB1>(sv);                                                 \
        sv = dpp_add<0x4E>(sv);                                                 \
        float pv = __expf(sv) * (VMUL);                                         \
        l += pv;                                                                \
        auto v01 = __builtin_amdgcn_cvt_pk_f32_fp8((int)(W).y, false);          \
        auto v23 = __builtin_amdgcn_cvt_pk_f32_fp8((int)(W).y, true);           \
        auto v45 = __builtin_amdgcn_cvt_pk_f32_fp8((int)(W).w, false);          \
        auto v67 = __builtin_amdgcn_cvt_pk_f32_fp8((int)(W).w, true);           \
        acc[0] += pv * v01[0]; acc[1] += pv * v01[1];                           \
        acc[2] += pv * v23[0]; acc[3] += pv * v23[1];                           \
        acc[4] += pv * v45[0]; acc[5] += pv * v45[1];                           \
        acc[6] += pv * v67[0]; acc[7] += pv * v67[1];                           \
    }

    unsigned e = beg;
    unsigned oA = 0, oB = 0, oC = 0, oD = 0;
    if (e + 8 <= end) {
        oA = ((unsigned)scol[e + sel])     << 9;
        oB = ((unsigned)scol[e + 2 + sel]) << 9;
        oC = ((unsigned)scol[e + 4 + sel]) << 9;
        oD = ((unsigned)scol[e + 6 + sel]) << 9;
    }
    while (e + 8 <= end) {
        uint4 wa = *reinterpret_cast<const uint4*>(kv8 + (oA + hlb));
        uint4 wb = *reinterpret_cast<const uint4*>(kv8 + (oB + hlb));
        uint4 wc = *reinterpret_cast<const uint4*>(kv8 + (oC + hlb));
        uint4 wd = *reinterpret_cast<const uint4*>(kv8 + (oD + hlb));
        e += 8;
        if (e + 8 <= end) {
            oA = ((unsigned)scol[e + sel])     << 9;
            oB = ((unsigned)scol[e + 2 + sel]) << 9;
            oC = ((unsigned)scol[e + 4 + sel]) << 9;
            oD = ((unsigned)scol[e + 6 + sel]) << 9;
        }
        PAIR_BODY(wa, 1.0f)
        PAIR_BODY(wb, 1.0f)
        PAIR_BODY(wc, 1.0f)
        PAIR_BODY(wd, 1.0f)
    }
    for (; e + 2 <= end; e += 2) {
        unsigned o0 = ((unsigned)scol[e + sel]) << 9;
        uint4 wa = *reinterpret_cast<const uint4*>(kv8 + (o0 + hlb));
        PAIR_BODY(wa, 1.0f)
    }
    if (e < end) {
        unsigned o0 = ((unsigned)scol[e]) << 9;
        uint4 wa = *reinterpret_cast<const uint4*>(kv8 + (o0 + hlb));
        PAIR_BODY(wa, sel ? 0.0f : 1.0f)
    }
#undef PAIR_BODY

    l += __shfl_xor(l, 32);
#pragma unroll
    for (int i = 0; i < 8; i++) acc[i] += __shfl_xor(acc[i], 32);

    float inv_l = (l > 0.f) ? 1.f / l : 0.f;

    float tv[8];
    {
        float xv[8];
        uint4 u = *reinterpret_cast<const uint4*>(xres + (size_t)n * D_MODEL + hl * 8);
        unpack_bf8(u, xv);
#pragma unroll
        for (int i = 0; i < 8; i++) tv[i] = acc[i] * inv_l + xv[i];
    }

    float s = 0.f, s2 = 0.f;
#pragma unroll
    for (int i = 0; i < 8; i++) { s += tv[i]; s2 += tv[i] * tv[i]; }
#pragma unroll
    for (int off = 1; off <= 16; off <<= 1) {
        s  += __shfl_xor(s, off);
        s2 += __shfl_xor(s2, off);
    }
    float mean = s * (1.f / (float)D_MODEL);
    float var  = s2 * (1.f / (float)D_MODEL) - mean * mean;
    float inv  = rsqrtf(var + LN_EPS);

    if (sel == 0) {
        const float4* gp = reinterpret_cast<const float4*>(g);
        const float4* bp = reinterpret_cast<const float4*>(bb);
        float4 g0 = gp[hl * 2], g1 = gp[hl * 2 + 1];
        float4 b0 = bp[hl * 2], b1 = bp[hl * 2 + 1];
        float gv[8] = {g0.x, g0.y, g0.z, g0.w, g1.x, g1.y, g1.z, g1.w};
        float bv[8] = {b0.x, b0.y, b0.z, b0.w, b1.x, b1.y, b1.z, b1.w};
        u16x8 o;
#pragma unroll
        for (int i = 0; i < 8; i++)
            o[i] = bfbits((tv[i] - mean) * inv * gv[i] + bv[i]);
        *reinterpret_cast<u16x8*>(xn + (size_t)n * D_MODEL + hl * 8) = o;
    }
}

extern "C" void kernel_launch(void* const* d_in, const int* in_sizes, int n_in,
                              void* d_out, int out_size, void* d_ws, size_t ws_size,
                              hipStream_t stream) {
    const float* x     = (const float*)d_in[0];
    const int*   ei    = (const int*)d_in[1];
    const float* w_qkv = (const float*)d_in[2];
    const float* b_qkv = (const float*)d_in[3];
    const float* ln1_g = (const float*)d_in[4];
    const float* ln1_b = (const float*)d_in[5];
    const float* ln2_g = (const float*)d_in[6];
    const float* ln2_b = (const float*)d_in[7];
    const float* w1    = (const float*)d_in[8];
    const float* b1    = (const float*)d_in[9];
    const float* w2    = (const float*)d_in[10];
    const float* b2    = (const float*)d_in[11];
    const int* rows = ei;
    const int* cols = ei + E_EDGES;

    // workspace layout (bytes), total < 179,200,000 (known-good footprint):
    //   [0,          25,600,000)  qb  bf16 N*256 } dead after att_agg;
    //   [25,600,000, 51,200,000)  kv8 fp8  N*512 } region [0,102.4e6) reused as hbuf
    //   [102,400,000,128,000,000) xb bf16 N*256 (live through att_agg: residual src)
    //   [128,000,000,128,393,216) wtq bf16 768x256 (perm cols)
    //   [128,400,000,128,924,288) wt1 bf16 1024x256 (perm cols)
    //   [129,000,000,129,524,288) wt2 bf16 256x1024
    //   [129,600,000,129,800,000) counts u32 N
    //   [129,800,000,130,000,004) offsets u32 N+1 (block-local prefixes)
    //   [130,000,008,130,200,008) cursor u32 N
    //   [130,200,008,133,400,008) scol i32 E
    //   [133,400,008,133,401,032) bsum u32 256 (bsum[200] = scan ticket counter)
    //   [133,401,032,133,402,060) bpre u32 257
    //   [133,500,000,133,503,072) bqp f32 768 (perm qkv bias)
    //   [133,510,000,133,514,096) b1p f32 1024 (perm ffn1 bias)
    //   [153,600,000,179,200,000) xn bf16 N*256
    char* ws = (char*)d_ws;
    __hip_bfloat16* qb      = (__hip_bfloat16*)(ws + 0);
    unsigned char*  kv8     = (unsigned char*)(ws + 25600000);
    __hip_bfloat16* hbuf    = (__hip_bfloat16*)(ws + 0);
    __hip_bfloat16* xb      = (__hip_bfloat16*)(ws + 102400000);
    __hip_bfloat16* wtq     = (__hip_bfloat16*)(ws + 128000000);
    __hip_bfloat16* wt1     = (__hip_bfloat16*)(ws + 128400000);
    __hip_bfloat16* wt2     = (__hip_bfloat16*)(ws + 129000000);
    unsigned*       counts  = (unsigned*)(ws + 129600000);
    unsigned*       offsets = (unsigned*)(ws + 129800000);
    unsigned*       cursor  = (unsigned*)(ws + 130000008);
    int*            scol    = (int*)(ws + 130200008);
    unsigned*       bsum    = (unsigned*)(ws + 133400008);
    unsigned*       bpre    = (unsigned*)(ws + 133401032);
    float*          bqp     = (float*)(ws + 133500000);
    float*          b1p     = (float*)(ws + 133510000);
    __hip_bfloat16* xn      = (__hip_bfloat16*)(ws + 153600000);
    unsigned*       scnt    = bsum + 200;    // unused bsum slot (only 196 blocks)

    const int nbM = (N_NODES + 127) / 128;   // 391

    // zero counts (stream-ordered before prep's atomics); cursor zeroed in scan_blk
    hipMemsetAsync(counts, 0, N_NODES * sizeof(unsigned), stream);

    // prep (block roles): edge-count + x->bf16 + TILED wtq transpose + bqp + scnt
    prep_kernel<<<NB_PREP, 256, 0, stream>>>(
        rows, counts, x, (unsigned short*)xb, w_qkv, wtq, b_qkv, bqp, scnt);

    // CSR scan: single kernel (StreamScan) + cursor zeroing
    scan_blk_kernel<<<NB_SCAN, 256, 0, stream>>>(counts, offsets, bsum, bpre, scnt, cursor);

    // MEGA: roles striped 1:2 (aux:gemm) through the grid for true co-residency
    mega_kernel<<<NB_MEGA, 256, 0, stream>>>(
        xb, wtq, bqp, qb, kv8,
        rows, cols, offsets, bpre, cursor, scol,
        w1, wt1, w2, wt2, b1, b1p, N_NODES);

    // attention (pair-edge, 8-edge pipelined, DPP reduce, bf16 residual) + LN1 -> xn
    att_agg_kernel<<<(N_NODES + 1) / 2, 128, 0, stream>>>(qb, kv8, offsets, bpre, scol,
                                                          xb, ln1_g, ln1_b, xn);

    // hbuf = relu(xn @ wt1^T + b1p), counted-vmcnt 3-buf pipeline (reverted best form)
    mfma_gemm<true, 1, 256><<<dim3(F_FFN / 128, nbM), 256, 0, stream>>>(
        xn, wt1, b1p, hbuf, N_NODES, F_FFN);

    // d_out = LN2(hbuf @ wt2^T + b2 + xn)   (fused, f32 out; 2-phase 40KB dbuf)
    ffn2_ln_kernel<<<(N_NODES + 63) / 64, 512, 0, stream>>>(hbuf, wt2, b2, xn, ln2_g, ln2_b,
                                                            (float*)d_out, N_NODES);
}